// Round 1
// baseline (260.265 us; speedup 1.0000x reference)
//
#include <hip/hip_runtime.h>

#define SEQ_T 2048
#define NHEAD 16

typedef unsigned short u16;
typedef __attribute__((ext_vector_type(4))) float f32x4;
typedef __attribute__((ext_vector_type(8))) short short8;
typedef __attribute__((ext_vector_type(4))) unsigned short u16x4;

__device__ __forceinline__ u16 f2bf(float f) {
  unsigned u = __float_as_uint(f);
  unsigned r = (u + 0x7FFFu + ((u >> 16) & 1u)) >> 16;
  return (u16)r;
}

__device__ __forceinline__ void gload_lds16(const void* g, void* l) {
  __builtin_amdgcn_global_load_lds((const __attribute__((address_space(1))) void*)g,
                                   (__attribute__((address_space(3))) void*)l, 16, 0, 0);
}

// ---------------------------------------------------------------- convert
__global__ __launch_bounds__(256) void cvt_all(
    const float* __restrict__ x, const float* __restrict__ wq, const float* __restrict__ wk,
    const float* __restrict__ wv, const float* __restrict__ wo,
    u16* __restrict__ xb, u16* __restrict__ wqb, u16* __restrict__ wkb,
    u16* __restrict__ wvb, u16* __restrict__ wob) {
  const int which = blockIdx.y;
  const float* s; u16* d; int n4;
  if (which == 0)      { s = x;  d = xb;  n4 = 1048576; }
  else if (which == 1) { s = wq; d = wqb; n4 = 262144; }
  else if (which == 2) { s = wk; d = wkb; n4 = 262144; }
  else if (which == 3) { s = wv; d = wvb; n4 = 262144; }
  else                 { s = wo; d = wob; n4 = 262144; }
  const int i = blockIdx.x * 256 + threadIdx.x;
  if (i >= n4) return;
  const float4 v = ((const float4*)s)[i];
  u16x4 o;
  o[0] = f2bf(v.x); o[1] = f2bf(v.y); o[2] = f2bf(v.z); o[3] = f2bf(v.w);
  ((u16x4*)d)[i] = o;
}

// ------------------------------------------------- shared GEMM main loop
// C[128x128] = A[128rows x 1024] * B[128rows x 1024]^T  (both row-major [rows][K], NT)
// 256 threads = 4 waves in 2x2; each wave 64x64 = 4x4 frags of 16x16.
// LDS: [buf][A|B][128][32] bf16, 16B chunks XOR-swizzled by (row&3).
static __device__ __forceinline__ void gemm_core(
    const u16* __restrict__ A, const u16* __restrict__ Bmat,
    u16* lds, int row0, int col0, int tid, f32x4 acc[4][4]) {
  const int wv = tid >> 6, lane = tid & 63;
  const int wr = wv >> 1, wc = wv & 1;
  const int lr15 = lane & 15, lg = lane >> 4;

  auto stage = [&](int buf, int kt) {
    const int k0 = kt * 32;
#pragma unroll
    for (int v = 0; v < 2; ++v) {
      const int slot = v * 256 + tid;        // 16B slots 0..511 (row = slot/4, chunk = slot%4)
      const int r = slot >> 2, c = slot & 3;
      const int sc = c ^ (r & 3);            // pre-swizzled global source (m173)
      const u16* gA = A    + (size_t)(row0 + r) * 1024 + k0 + sc * 8;
      const u16* gB = Bmat + (size_t)(col0 + r) * 1024 + k0 + sc * 8;
      gload_lds16(gA, lds + buf * 8192 +        v * 2048 + wv * 512);
      gload_lds16(gB, lds + buf * 8192 + 4096 + v * 2048 + wv * 512);
    }
  };

  stage(0, 0);
  __syncthreads();
  for (int t = 0; t < 32; ++t) {
    if (t < 31) stage((t + 1) & 1, t + 1);   // async prefetch overlaps compute
    const u16* lA = lds + (t & 1) * 8192;
    const u16* lB = lA + 4096;
    short8 a[4], b[4];
#pragma unroll
    for (int m = 0; m < 4; ++m) {
      const int row = wr * 64 + m * 16 + lr15;
      const int swz = lg ^ (row & 3);
      a[m] = *(const short8*)(lA + row * 32 + swz * 8);
    }
#pragma unroll
    for (int n = 0; n < 4; ++n) {
      const int row = wc * 64 + n * 16 + lr15;
      const int swz = lg ^ (row & 3);
      b[n] = *(const short8*)(lB + row * 32 + swz * 8);
    }
#pragma unroll
    for (int m = 0; m < 4; ++m)
#pragma unroll
      for (int n = 0; n < 4; ++n)
        acc[m][n] = __builtin_amdgcn_mfma_f32_16x16x32_bf16(a[m], b[n], acc[m][n], 0, 0, 0);
    __syncthreads();                          // drains vmcnt -> next buf ready
  }
}

// ---------------------------------------------------- fused QKV projection
// grid (24, 32): blockIdx.x/8 selects Q/K/V, (blockIdx.x&7)*128 = col tile.
// Q,K out: [B,H,T,64] bf16.  V out: [B,H,64,T] bf16 (pre-transposed for PV).
__global__ __launch_bounds__(256) void gemm_qkv(
    const u16* __restrict__ X,
    const u16* __restrict__ WQ, const u16* __restrict__ WK, const u16* __restrict__ WV,
    const float* __restrict__ BQ, const float* __restrict__ BK, const float* __restrict__ BV,
    u16* __restrict__ OQ, u16* __restrict__ OK, u16* __restrict__ OV) {
  __shared__ u16 lds[2 * 2 * 4096];
  const int which = blockIdx.x >> 3;
  const int col0 = (blockIdx.x & 7) * 128;
  const int row0 = blockIdx.y * 128;
  const u16* W = (which == 0) ? WQ : ((which == 1) ? WK : WV);
  const float* bias = (which == 0) ? BQ : ((which == 1) ? BK : BV);
  u16* out = (which == 0) ? OQ : ((which == 1) ? OK : OV);
  const int tid = threadIdx.x;
  f32x4 acc[4][4];
#pragma unroll
  for (int m = 0; m < 4; ++m)
#pragma unroll
    for (int n = 0; n < 4; ++n) acc[m][n] = (f32x4){0.f, 0.f, 0.f, 0.f};

  gemm_core(X, W, lds, row0, col0, tid, acc);

  const int wv = tid >> 6, lane = tid & 63;
  const int wr = wv >> 1, wc = wv & 1;
#pragma unroll
  for (int n = 0; n < 4; ++n) {
    const int col = col0 + wc * 64 + n * 16 + (lane & 15);
    const float bc = bias[col];
    const int hh = col >> 6, hd = col & 63;
#pragma unroll
    for (int m = 0; m < 4; ++m) {
#pragma unroll
      for (int r = 0; r < 4; ++r) {
        const int row = row0 + wr * 64 + m * 16 + (lane >> 4) * 4 + r;
        const int b_ = row >> 11, tt = row & 2047;
        const u16 h = f2bf(acc[m][n][r] + bc);
        if (which != 2) {
          out[(((size_t)(b_ * NHEAD + hh) * SEQ_T + tt) << 6) + hd] = h;
        } else {
          out[(((size_t)(b_ * NHEAD + hh) << 6) + hd) * SEQ_T + tt] = h;
        }
      }
    }
  }
}

// ------------------------------------------------------ sigmoid attention
// grid (32, 32): x = q-tile of 64 rows, y = b*H+h. 4 waves, each 16 q-rows.
// Streaming: oacc += sigma(QK/8) @ V, den += sigma; no rescale needed.
__global__ __launch_bounds__(256) void attn_sig(
    const u16* __restrict__ Q, const u16* __restrict__ K,
    const u16* __restrict__ Vt, u16* __restrict__ AO) {
  __shared__ u16 ldsK[2][4096];   // [64 s][64 hd], rows 128B, chunk^(row&7) swizzle
  __shared__ u16 ldsV[2][4096];   // [64 hd][64 s]
  __shared__ u16 ldsP[4][1024];   // per-wave [16 t][64 s]
  const int tid = threadIdx.x, wv = tid >> 6, lane = tid & 63;
  const int lr15 = lane & 15, lg = lane >> 4;
  const int bh = blockIdx.y;
  const int q0 = blockIdx.x * 64 + wv * 16;
  const u16* Qb = Q  + (size_t)bh * SEQ_T * 64;
  const u16* Kb = K  + (size_t)bh * SEQ_T * 64;
  const u16* Vb = Vt + (size_t)bh * 64 * SEQ_T;

  short8 qf[2];
#pragma unroll
  for (int kk = 0; kk < 2; ++kk)
    qf[kk] = *(const short8*)(Qb + (size_t)(q0 + lr15) * 64 + kk * 32 + lg * 8);

  f32x4 oacc[4];
#pragma unroll
  for (int n = 0; n < 4; ++n) oacc[n] = (f32x4){0.f, 0.f, 0.f, 0.f};
  f32x4 den = (f32x4){0.f, 0.f, 0.f, 0.f};

  auto stage = [&](int buf, int s0) {
#pragma unroll
    for (int v = 0; v < 2; ++v) {
      const int slot = v * 256 + tid;        // row = slot/8 (128B rows), chunk = slot%8
      const int r = slot >> 3, c = slot & 7;
      const int sc = c ^ (r & 7);
      gload_lds16(Kb + (size_t)(s0 + r) * 64 + sc * 8, &ldsK[buf][v * 2048 + wv * 512]);
      gload_lds16(Vb + (size_t)r * SEQ_T + s0 + sc * 8, &ldsV[buf][v * 2048 + wv * 512]);
    }
  };

  stage(0, 0);
  __syncthreads();

  for (int st = 0; st < 32; ++st) {
    if (st < 31) stage((st + 1) & 1, (st + 1) * 64);
    const u16* lK = ldsK[st & 1];
    const u16* lV = ldsV[st & 1];

    // S[16t x 64s] = Q . K^T
    f32x4 sacc[4];
#pragma unroll
    for (int n = 0; n < 4; ++n) sacc[n] = (f32x4){0.f, 0.f, 0.f, 0.f};
#pragma unroll
    for (int kk = 0; kk < 2; ++kk) {
#pragma unroll
      for (int n = 0; n < 4; ++n) {
        const int row = n * 16 + lr15;
        const int swz = (kk * 4 + lg) ^ (row & 7);
        const short8 kf = *(const short8*)(lK + row * 64 + swz * 8);
        sacc[n] = __builtin_amdgcn_mfma_f32_16x16x32_bf16(qf[kk], kf, sacc[n], 0, 0, 0);
      }
    }
    // sigmoid + denominator + P -> LDS (bf16, swizzled)
#pragma unroll
    for (int n = 0; n < 4; ++n) {
      const int pc = n * 16 + lr15;
#pragma unroll
      for (int r = 0; r < 4; ++r) {
        const int pr = lg * 4 + r;
        const float xv = sacc[n][r] * 0.125f;
        const float g = __fdividef(1.0f, 1.0f + __expf(-xv));
        den[r] += g;
        const int swz = (pc >> 3) ^ (pr & 7);
        ldsP[wv][pr * 64 + swz * 8 + (pc & 7)] = f2bf(g);
      }
    }
    // O += P . V   (per-wave LDS, no barrier needed before reads)
#pragma unroll
    for (int kk = 0; kk < 2; ++kk) {
      const int pswz = (kk * 4 + lg) ^ (lr15 & 7);
      const short8 pf = *(const short8*)(&ldsP[wv][lr15 * 64 + pswz * 8]);
#pragma unroll
      for (int n = 0; n < 4; ++n) {
        const int vr = n * 16 + lr15;
        const int vswz = (kk * 4 + lg) ^ (vr & 7);
        const short8 vf = *(const short8*)(lV + vr * 64 + vswz * 8);
        oacc[n] = __builtin_amdgcn_mfma_f32_16x16x32_bf16(pf, vf, oacc[n], 0, 0, 0);
      }
    }
    __syncthreads();
  }

  // reduce den across the 16 lanes sharing a row group
#pragma unroll
  for (int m = 1; m < 16; m <<= 1) {
#pragma unroll
    for (int r = 0; r < 4; ++r) den[r] += __shfl_xor(den[r], m, 64);
  }
  const int b_ = bh >> 4, hh = bh & 15;
#pragma unroll
  for (int n = 0; n < 4; ++n) {
    const int hd = n * 16 + lr15;
#pragma unroll
    for (int r = 0; r < 4; ++r) {
      const int tt = q0 + lg * 4 + r;
      const float o = __fdividef(oacc[n][r], den[r] + 1e-6f);
      AO[((size_t)(b_ * SEQ_T + tt) << 10) + hh * 64 + hd] = f2bf(o);
    }
  }
}

// ------------------------------------------- output projection + residual
__global__ __launch_bounds__(256) void gemm_out(
    const u16* __restrict__ A, const u16* __restrict__ W,
    const float* __restrict__ bias, const float* __restrict__ X,
    const float* __restrict__ alphap, float* __restrict__ out) {
  __shared__ u16 lds[2 * 2 * 4096];
  const int col0 = blockIdx.x * 128, row0 = blockIdx.y * 128;
  const int tid = threadIdx.x;
  f32x4 acc[4][4];
#pragma unroll
  for (int m = 0; m < 4; ++m)
#pragma unroll
    for (int n = 0; n < 4; ++n) acc[m][n] = (f32x4){0.f, 0.f, 0.f, 0.f};

  gemm_core(A, W, lds, row0, col0, tid, acc);

  const float alpha = alphap[0];
  const int wv = tid >> 6, lane = tid & 63;
  const int wr = wv >> 1, wc = wv & 1;
#pragma unroll
  for (int n = 0; n < 4; ++n) {
    const int col = col0 + wc * 64 + n * 16 + (lane & 15);
    const float bc = bias[col];
#pragma unroll
    for (int m = 0; m < 4; ++m) {
#pragma unroll
      for (int r = 0; r < 4; ++r) {
        const int row = row0 + wr * 64 + m * 16 + (lane >> 4) * 4 + r;
        const size_t off = ((size_t)row << 10) + col;
        out[off] = X[off] + alpha * (acc[m][n][r] + bc);
      }
    }
  }
}

// ------------------------------------------------------------------ launch
extern "C" void kernel_launch(void* const* d_in, const int* in_sizes, int n_in,
                              void* d_out, int out_size, void* d_ws, size_t ws_size,
                              hipStream_t stream) {
  const float* x  = (const float*)d_in[0];
  const float* wq = (const float*)d_in[1];
  const float* bq = (const float*)d_in[2];
  const float* wk = (const float*)d_in[3];
  const float* bk = (const float*)d_in[4];
  const float* wv = (const float*)d_in[5];
  const float* bv = (const float*)d_in[6];
  const float* wo = (const float*)d_in[7];
  const float* bo = (const float*)d_in[8];
  const float* alpha = (const float*)d_in[9];
  float* out = (float*)d_out;
  char* ws = (char*)d_ws;
  const size_t MB = 1u << 20;
  u16* xb  = (u16*)(ws + 0 * MB);    // [4096,1024] bf16
  u16* wqb = (u16*)(ws + 8 * MB);
  u16* wkb = (u16*)(ws + 10 * MB);
  u16* wvb = (u16*)(ws + 12 * MB);
  u16* wob = (u16*)(ws + 14 * MB);
  u16* qw  = (u16*)(ws + 16 * MB);   // [B,H,T,64]
  u16* kw  = (u16*)(ws + 24 * MB);   // [B,H,T,64]
  u16* vtw = (u16*)(ws + 32 * MB);   // [B,H,64,T]
  u16* aow = (u16*)(ws + 40 * MB);   // [4096,1024]

  cvt_all<<<dim3(4096, 5), 256, 0, stream>>>(x, wq, wk, wv, wo, xb, wqb, wkb, wvb, wob);
  gemm_qkv<<<dim3(24, 32), 256, 0, stream>>>(xb, wqb, wkb, wvb, bq, bk, bv, qw, kw, vtw);
  attn_sig<<<dim3(32, 32), 256, 0, stream>>>(qw, kw, vtw, aow);
  gemm_out<<<dim3(8, 32), 256, 0, stream>>>(aow, wob, bo, x, alpha, out);
}

// Round 2
// 208.088 us; speedup vs baseline: 1.2507x; 1.2507x over previous
//
#include <hip/hip_runtime.h>

#define SEQ_T 2048
#define NHEAD 16

typedef unsigned short u16;
typedef __attribute__((ext_vector_type(4))) float f32x4;
typedef __attribute__((ext_vector_type(8))) short short8;
typedef __attribute__((ext_vector_type(4))) unsigned short u16x4;
typedef __attribute__((ext_vector_type(2))) unsigned int u32x2;

__device__ __forceinline__ u16 f2bf(float f) {
  unsigned u = __float_as_uint(f);
  unsigned r = (u + 0x7FFFu + ((u >> 16) & 1u)) >> 16;
  return (u16)r;
}

__device__ __forceinline__ void gload_lds16(const void* g, void* l) {
  __builtin_amdgcn_global_load_lds((const __attribute__((address_space(1))) void*)g,
                                   (__attribute__((address_space(3))) void*)l, 16, 0, 0);
}

// ---------------------------------------------------------------- convert
// 1D grid: [0,4096) -> x, then 1024 blocks per weight.
__global__ __launch_bounds__(256) void cvt_all(
    const float* __restrict__ x, const float* __restrict__ wq, const float* __restrict__ wk,
    const float* __restrict__ wv, const float* __restrict__ wo,
    u16* __restrict__ xb, u16* __restrict__ wqb, u16* __restrict__ wkb,
    u16* __restrict__ wvb, u16* __restrict__ wob) {
  const int bid = blockIdx.x;
  const float* s; u16* d; int base;
  if (bid < 4096) { s = x; d = xb; base = bid; }
  else {
    const int w = (bid - 4096) >> 10;
    base = (bid - 4096) & 1023;
    if (w == 0)      { s = wq; d = wqb; }
    else if (w == 1) { s = wk; d = wkb; }
    else if (w == 2) { s = wv; d = wvb; }
    else             { s = wo; d = wob; }
  }
  const int i = base * 256 + threadIdx.x;
  const float4 v = ((const float4*)s)[i];
  u16x4 o;
  o[0] = f2bf(v.x); o[1] = f2bf(v.y); o[2] = f2bf(v.z); o[3] = f2bf(v.w);
  ((u16x4*)d)[i] = o;
}

// ------------------------------------------------- shared GEMM main loop (128x128)
static __device__ __forceinline__ void gemm_core(
    const u16* __restrict__ A, const u16* __restrict__ Bmat,
    u16* lds, int row0, int col0, int tid, f32x4 acc[4][4]) {
  const int wv = tid >> 6, lane = tid & 63;
  const int wr = wv >> 1, wc = wv & 1;
  const int lr15 = lane & 15, lg = lane >> 4;

  auto stage = [&](int buf, int kt) {
    const int k0 = kt * 32;
#pragma unroll
    for (int v = 0; v < 2; ++v) {
      const int slot = v * 256 + tid;
      const int r = slot >> 2, c = slot & 3;
      const int sc = c ^ (r & 3);
      const u16* gA = A    + (size_t)(row0 + r) * 1024 + k0 + sc * 8;
      const u16* gB = Bmat + (size_t)(col0 + r) * 1024 + k0 + sc * 8;
      gload_lds16(gA, lds + buf * 8192 +        v * 2048 + wv * 512);
      gload_lds16(gB, lds + buf * 8192 + 4096 + v * 2048 + wv * 512);
    }
  };

  stage(0, 0);
  __syncthreads();
  for (int t = 0; t < 32; ++t) {
    if (t < 31) stage((t + 1) & 1, t + 1);
    const u16* lA = lds + (t & 1) * 8192;
    const u16* lB = lA + 4096;
    short8 a[4], b[4];
#pragma unroll
    for (int m = 0; m < 4; ++m) {
      const int row = wr * 64 + m * 16 + lr15;
      const int swz = lg ^ (row & 3);
      a[m] = *(const short8*)(lA + row * 32 + swz * 8);
    }
#pragma unroll
    for (int n = 0; n < 4; ++n) {
      const int row = wc * 64 + n * 16 + lr15;
      const int swz = lg ^ (row & 3);
      b[n] = *(const short8*)(lB + row * 32 + swz * 8);
    }
#pragma unroll
    for (int m = 0; m < 4; ++m)
#pragma unroll
      for (int n = 0; n < 4; ++n)
        acc[m][n] = __builtin_amdgcn_mfma_f32_16x16x32_bf16(a[m], b[n], acc[m][n], 0, 0, 0);
    __syncthreads();
  }
}

// ---------------------------------------------------- fused QKV projection
__global__ __launch_bounds__(256) void gemm_qkv(
    const u16* __restrict__ X,
    const u16* __restrict__ WQ, const u16* __restrict__ WK, const u16* __restrict__ WV,
    const float* __restrict__ BQ, const float* __restrict__ BK, const float* __restrict__ BV,
    u16* __restrict__ OQ, u16* __restrict__ OK, u16* __restrict__ OV) {
  __shared__ u16 lds[2 * 2 * 4096];
  const int which = blockIdx.x >> 3;
  const int col0 = (blockIdx.x & 7) * 128;
  const int row0 = blockIdx.y * 128;
  const u16* W = (which == 0) ? WQ : ((which == 1) ? WK : WV);
  const float* bias = (which == 0) ? BQ : ((which == 1) ? BK : BV);
  u16* out = (which == 0) ? OQ : ((which == 1) ? OK : OV);
  const int tid = threadIdx.x;
  f32x4 acc[4][4];
#pragma unroll
  for (int m = 0; m < 4; ++m)
#pragma unroll
    for (int n = 0; n < 4; ++n) acc[m][n] = (f32x4){0.f, 0.f, 0.f, 0.f};

  gemm_core(X, W, lds, row0, col0, tid, acc);

  const int wv = tid >> 6, lane = tid & 63;
  const int wr = wv >> 1, wc = wv & 1;
#pragma unroll
  for (int n = 0; n < 4; ++n) {
    const int col = col0 + wc * 64 + n * 16 + (lane & 15);
    const float bc = bias[col];
    const int hh = col >> 6, hd = col & 63;
#pragma unroll
    for (int m = 0; m < 4; ++m) {
#pragma unroll
      for (int r = 0; r < 4; ++r) {
        const int row = row0 + wr * 64 + m * 16 + (lane >> 4) * 4 + r;
        const int b_ = row >> 11, tt = row & 2047;
        const u16 h = f2bf(acc[m][n][r] + bc);
        if (which != 2) {
          out[(((size_t)(b_ * NHEAD + hh) * SEQ_T + tt) << 6) + hd] = h;
        } else {
          out[(((size_t)(b_ * NHEAD + hh) << 6) + hd) * SEQ_T + tt] = h;
        }
      }
    }
  }
}

// ------------------------------------------------------ sigmoid attention
// grid (16, 32): x = q-tile of 128 rows, y = b*H+h. 8 waves, each 16 q-rows.
// Swapped QK^T (S^T = mfma(K,Q)) so each lane owns s-runs for one q-row:
// sigmoid -> v_cvt_pk_bf16_f32 -> swizzled b64 P-LDS -> PV; den via mfma-ones.
__global__ __launch_bounds__(512) void attn_sig(
    const u16* __restrict__ Q, const u16* __restrict__ K,
    const u16* __restrict__ Vt, u16* __restrict__ AO) {
  __shared__ u16 ldsK[2][4096];   // [64 s][64 hd], chunk^(row&7) swizzle
  __shared__ u16 ldsV[2][4096];   // [64 hd][64 s], same swizzle
  __shared__ u16 ldsP[8][1024];   // per-wave [16 t][64 s] bf16, pair^t swizzle
  const int tid = threadIdx.x, wv = tid >> 6, lane = tid & 63;
  const int lr15 = lane & 15, lg = lane >> 4;
  const int bh = blockIdx.y;
  const int q0 = blockIdx.x * 128 + wv * 16;
  const u16* Qb = Q  + (size_t)bh * SEQ_T * 64;
  const u16* Kb = K  + (size_t)bh * SEQ_T * 64;
  const u16* Vb = Vt + (size_t)bh * 64 * SEQ_T;

  short8 qf[2];
#pragma unroll
  for (int kk = 0; kk < 2; ++kk)
    qf[kk] = *(const short8*)(Qb + (size_t)(q0 + lr15) * 64 + kk * 32 + lg * 8);

  short8 onesf;
#pragma unroll
  for (int i = 0; i < 8; ++i) onesf[i] = (short)0x3F80;

  f32x4 oacc[4];
#pragma unroll
  for (int n = 0; n < 4; ++n) oacc[n] = (f32x4){0.f, 0.f, 0.f, 0.f};
  f32x4 dacc = (f32x4){0.f, 0.f, 0.f, 0.f};

  auto stage = [&](int buf, int s0) {
    const int r = tid >> 3, c = tid & 7;
    const int sc = c ^ (r & 7);
    gload_lds16(Kb + (size_t)(s0 + r) * 64 + sc * 8, &ldsK[buf][wv * 512]);
    gload_lds16(Vb + (size_t)r * SEQ_T + s0 + sc * 8, &ldsV[buf][wv * 512]);
  };

  stage(0, 0);
  __syncthreads();

  const float SIGC = -0.18033688011112042f;  // -0.125 * log2(e)

  for (int st = 0; st < 32; ++st) {
    if (st < 31) stage((st + 1) & 1, (st + 1) * 64);
    const u16* lK = ldsK[st & 1];
    const u16* lV = ldsV[st & 1];

    // S^T[64s x 16t] = K . Q^T  (lane: t=lr15, s = n*16 + lg*4 + r)
    f32x4 sacc[4];
#pragma unroll
    for (int n = 0; n < 4; ++n) sacc[n] = (f32x4){0.f, 0.f, 0.f, 0.f};
#pragma unroll
    for (int kk = 0; kk < 2; ++kk) {
#pragma unroll
      for (int n = 0; n < 4; ++n) {
        const int row = n * 16 + lr15;
        const int swz = (kk * 4 + lg) ^ (row & 7);
        const short8 kf = *(const short8*)(lK + row * 64 + swz * 8);
        sacc[n] = __builtin_amdgcn_mfma_f32_16x16x32_bf16(kf, qf[kk], sacc[n], 0, 0, 0);
      }
    }
    // sigmoid -> packed bf16 -> P LDS (b64, pair^t swizzle)
#pragma unroll
    for (int n = 0; n < 4; ++n) {
      float g0 = __builtin_amdgcn_rcpf(1.0f + __builtin_amdgcn_exp2f(sacc[n][0] * SIGC));
      float g1 = __builtin_amdgcn_rcpf(1.0f + __builtin_amdgcn_exp2f(sacc[n][1] * SIGC));
      float g2 = __builtin_amdgcn_rcpf(1.0f + __builtin_amdgcn_exp2f(sacc[n][2] * SIGC));
      float g3 = __builtin_amdgcn_rcpf(1.0f + __builtin_amdgcn_exp2f(sacc[n][3] * SIGC));
      unsigned lo, hi;
      asm("v_cvt_pk_bf16_f32 %0, %1, %2" : "=v"(lo) : "v"(g0), "v"(g1));
      asm("v_cvt_pk_bf16_f32 %0, %1, %2" : "=v"(hi) : "v"(g2), "v"(g3));
      const int pw = ((n * 4 + lg) ^ lr15) * 4;
      *(u32x2*)(&ldsP[wv][lr15 * 64 + pw]) = (u32x2){lo, hi};
    }
    // O += P . V ; den += P . 1  (A-frag read back, pair^t swizzle)
#pragma unroll
    for (int kk = 0; kk < 2; ++kk) {
      const u32x2 pa = *(const u32x2*)(&ldsP[wv][lr15 * 64 + (((kk * 8 + lg * 2 + 0) ^ lr15) * 4)]);
      const u32x2 pb = *(const u32x2*)(&ldsP[wv][lr15 * 64 + (((kk * 8 + lg * 2 + 1) ^ lr15) * 4)]);
      union { u32x2 u[2]; short8 s; } cv;
      cv.u[0] = pa; cv.u[1] = pb;
      const short8 pf = cv.s;
#pragma unroll
      for (int n = 0; n < 4; ++n) {
        const int vr = n * 16 + lr15;
        const int vswz = (kk * 4 + lg) ^ (vr & 7);
        const short8 vf = *(const short8*)(lV + vr * 64 + vswz * 8);
        oacc[n] = __builtin_amdgcn_mfma_f32_16x16x32_bf16(pf, vf, oacc[n], 0, 0, 0);
      }
      dacc = __builtin_amdgcn_mfma_f32_16x16x32_bf16(pf, onesf, dacc, 0, 0, 0);
    }
    __syncthreads();
  }

  const int b_ = bh >> 4, hh = bh & 15;
  f32x4 rden;
#pragma unroll
  for (int r = 0; r < 4; ++r) rden[r] = __builtin_amdgcn_rcpf(dacc[r] + 1e-6f);
#pragma unroll
  for (int n = 0; n < 4; ++n) {
    const int hd = n * 16 + lr15;
#pragma unroll
    for (int r = 0; r < 4; ++r) {
      const int tt = q0 + lg * 4 + r;
      const float o = oacc[n][r] * rden[r];
      AO[((size_t)(b_ * SEQ_T + tt) << 10) + hh * 64 + hd] = f2bf(o);
    }
  }
}

// ------------------------------------------- output projection + residual
// 64x128 tile, 512 blocks = 2/CU. 4 waves split cols (wave = 32 cols).
__global__ __launch_bounds__(256) void gemm_out(
    const u16* __restrict__ A, const u16* __restrict__ W,
    const float* __restrict__ bias, const float* __restrict__ X,
    const float* __restrict__ alphap, float* __restrict__ out) {
  __shared__ u16 lds[2 * 6144];   // per buf: A 64x32 (2048) + B 128x32 (4096)
  const int col0 = blockIdx.x * 128, row0 = blockIdx.y * 64;
  const int tid = threadIdx.x, wv = tid >> 6, lane = tid & 63;
  const int lr15 = lane & 15, lg = lane >> 4;
  f32x4 acc[4][2];
#pragma unroll
  for (int m = 0; m < 4; ++m)
#pragma unroll
    for (int n = 0; n < 2; ++n) acc[m][n] = (f32x4){0.f, 0.f, 0.f, 0.f};

  auto stage = [&](int buf, int kt) {
    const int k0 = kt * 32;
    {
      const int r = tid >> 2, c = tid & 3;
      const int sc = c ^ (r & 3);
      gload_lds16(A + (size_t)(row0 + r) * 1024 + k0 + sc * 8, lds + buf * 6144 + wv * 512);
    }
#pragma unroll
    for (int v = 0; v < 2; ++v) {
      const int slot = v * 256 + tid;
      const int r = slot >> 2, c = slot & 3;
      const int sc = c ^ (r & 3);
      gload_lds16(W + (size_t)(col0 + r) * 1024 + k0 + sc * 8,
                  lds + buf * 6144 + 2048 + v * 2048 + wv * 512);
    }
  };

  stage(0, 0);
  __syncthreads();
  for (int t = 0; t < 32; ++t) {
    if (t < 31) stage((t + 1) & 1, t + 1);
    const u16* lA = lds + (t & 1) * 6144;
    const u16* lB = lA + 2048;
    short8 a[4], b[2];
#pragma unroll
    for (int m = 0; m < 4; ++m) {
      const int row = m * 16 + lr15;
      a[m] = *(const short8*)(lA + row * 32 + (lg ^ (row & 3)) * 8);
    }
#pragma unroll
    for (int n = 0; n < 2; ++n) {
      const int row = wv * 32 + n * 16 + lr15;
      b[n] = *(const short8*)(lB + row * 32 + (lg ^ (row & 3)) * 8);
    }
#pragma unroll
    for (int m = 0; m < 4; ++m)
#pragma unroll
      for (int n = 0; n < 2; ++n)
        acc[m][n] = __builtin_amdgcn_mfma_f32_16x16x32_bf16(a[m], b[n], acc[m][n], 0, 0, 0);
    __syncthreads();
  }

  const float alpha = alphap[0];
#pragma unroll
  for (int n = 0; n < 2; ++n) {
    const int col = col0 + wv * 32 + n * 16 + lr15;
    const float bc = bias[col];
#pragma unroll
    for (int m = 0; m < 4; ++m) {
#pragma unroll
      for (int r = 0; r < 4; ++r) {
        const int row = row0 + m * 16 + lg * 4 + r;
        const size_t off = ((size_t)row << 10) + col;
        out[off] = X[off] + alpha * (acc[m][n][r] + bc);
      }
    }
  }
}

// ------------------------------------------------------------------ launch
extern "C" void kernel_launch(void* const* d_in, const int* in_sizes, int n_in,
                              void* d_out, int out_size, void* d_ws, size_t ws_size,
                              hipStream_t stream) {
  const float* x  = (const float*)d_in[0];
  const float* wq = (const float*)d_in[1];
  const float* bq = (const float*)d_in[2];
  const float* wk = (const float*)d_in[3];
  const float* bk = (const float*)d_in[4];
  const float* wv = (const float*)d_in[5];
  const float* bv = (const float*)d_in[6];
  const float* wo = (const float*)d_in[7];
  const float* bo = (const float*)d_in[8];
  const float* alpha = (const float*)d_in[9];
  float* out = (float*)d_out;
  char* ws = (char*)d_ws;
  const size_t MB = 1u << 20;
  u16* xb  = (u16*)(ws + 0 * MB);
  u16* wqb = (u16*)(ws + 8 * MB);
  u16* wkb = (u16*)(ws + 10 * MB);
  u16* wvb = (u16*)(ws + 12 * MB);
  u16* wob = (u16*)(ws + 14 * MB);
  u16* qw  = (u16*)(ws + 16 * MB);   // [B,H,T,64]
  u16* kw  = (u16*)(ws + 24 * MB);   // [B,H,T,64]
  u16* vtw = (u16*)(ws + 32 * MB);   // [B,H,64,T]
  u16* aow = (u16*)(ws + 40 * MB);   // [4096,1024]

  cvt_all<<<8192, 256, 0, stream>>>(x, wq, wk, wv, wo, xb, wqb, wkb, wvb, wob);
  gemm_qkv<<<dim3(24, 32), 256, 0, stream>>>(xb, wqb, wkb, wvb, bq, bk, bv, qw, kw, vtw);
  attn_sig<<<dim3(16, 32), 512, 0, stream>>>(qw, kw, vtw, aow);
  gemm_out<<<dim3(8, 64), 256, 0, stream>>>(aow, wob, bo, x, alpha, out);
}